// Round 3
// 484.106 us; speedup vs baseline: 1.1266x; 1.1266x over previous
//
#include <hip/hip_runtime.h>
#include <math.h>

#define DDIM 512
#define NS 96
#define SPITCH 132
#define KMASK 0xFFFFF800
#define NEG_INF (-3.0e38f)
#define IMAX 0x7fffffff

typedef _Float16 f16x8 __attribute__((ext_vector_type(8)));
typedef float    f32x4 __attribute__((ext_vector_type(4)));
typedef int      i32x4 __attribute__((ext_vector_type(4)));

__device__ __forceinline__ int imin(int a, int b) { return a < b ? a : b; }
__device__ __forceinline__ int imax(int a, int b) { return a > b ? a : b; }

// exact median-of-3 (VOP3, single instruction) — top-4 insert becomes 1 max + 3 med3
__device__ __forceinline__ int med3(int a, int b, int c) {
    int d;
    asm("v_med3_i32 %0, %1, %2, %3" : "=v"(d) : "v"(a), "v"(b), "v"(c));
    return d;
}

__device__ __forceinline__ void glds16(const void* g, void* l) {
    __builtin_amdgcn_global_load_lds((const __attribute__((address_space(1))) void*)g,
                                     (__attribute__((address_space(3))) void*)l, 16, 0, 0);
}

// K-loop barrier: wait own staging loads (issued one full iteration ago -> latency hidden),
// then raw barrier. NO lgkm/vm drain beyond what's needed -> prefetch survives.
#define KBAR() do { asm volatile("s_waitcnt vmcnt(0)" ::: "memory"); \
                    __builtin_amdgcn_s_barrier();                    \
                    asm volatile("" ::: "memory"); } while (0)
// Epilogue barrier: publish LDS writes (lgkm only) — keeps cross-chunk glds prefetch in flight.
#define EBAR() do { asm volatile("s_waitcnt lgkmcnt(0)" ::: "memory"); \
                    __builtin_amdgcn_s_barrier();                      \
                    asm volatile("" ::: "memory"); } while (0)

// fp32 rows -> f16 tile [chunk*16+ks][128 rows][32 halves] + reciprocal norms.
// thread = (row r = t>>1, half hf = t&1): stores are perfectly coalesced dwordx4;
// read pairs (hf=0/1) cover one 128-B line.
__global__ __launch_bounds__(256) void split_tile_k(const float* __restrict__ src,
                                                    unsigned* __restrict__ tile,
                                                    float* __restrict__ rn, int rows) {
    const int t = threadIdx.x;
    const int r = t >> 1, hf = t & 1;
    const int R = blockIdx.x * 128 + r;
    const bool valid = R < rows;
    const float* srow = src + (size_t)(valid ? R : 0) * DDIM + hf * 16;
    float ss = 0.f;
    for (int ks = 0; ks < 16; ++ks) {
        float4 v0 = *(const float4*)(srow + ks * 32);
        float4 v1 = *(const float4*)(srow + ks * 32 + 4);
        float4 v2 = *(const float4*)(srow + ks * 32 + 8);
        float4 v3 = *(const float4*)(srow + ks * 32 + 12);
        ss += v0.x*v0.x + v0.y*v0.y + v0.z*v0.z + v0.w*v0.w
            + v1.x*v1.x + v1.y*v1.y + v1.z*v1.z + v1.w*v1.w
            + v2.x*v2.x + v2.y*v2.y + v2.z*v2.z + v2.w*v2.w
            + v3.x*v3.x + v3.y*v3.y + v3.z*v3.z + v3.w*v3.w;
        unsigned o[8];
        o[0] = __builtin_bit_cast(unsigned, __builtin_amdgcn_cvt_pkrtz(v0.x, v0.y));
        o[1] = __builtin_bit_cast(unsigned, __builtin_amdgcn_cvt_pkrtz(v0.z, v0.w));
        o[2] = __builtin_bit_cast(unsigned, __builtin_amdgcn_cvt_pkrtz(v1.x, v1.y));
        o[3] = __builtin_bit_cast(unsigned, __builtin_amdgcn_cvt_pkrtz(v1.z, v1.w));
        o[4] = __builtin_bit_cast(unsigned, __builtin_amdgcn_cvt_pkrtz(v2.x, v2.y));
        o[5] = __builtin_bit_cast(unsigned, __builtin_amdgcn_cvt_pkrtz(v2.z, v2.w));
        o[6] = __builtin_bit_cast(unsigned, __builtin_amdgcn_cvt_pkrtz(v3.x, v3.y));
        o[7] = __builtin_bit_cast(unsigned, __builtin_amdgcn_cvt_pkrtz(v3.z, v3.w));
        if (!valid) {
            #pragma unroll
            for (int q = 0; q < 8; ++q) o[q] = 0u;   // zero-pad OOB bank rows
        }
        unsigned* dst = tile + ((size_t)(blockIdx.x * 16 + ks) * 128 + r) * 16 + hf * 8;
        *(i32x4*)dst       = *(i32x4*)o;
        *(i32x4*)(dst + 4) = *(i32x4*)(o + 4);
    }
    ss += __shfl_xor(ss, 1, 64);
    // write rn for OOB rows too (0.0f): keys for padded columns become exactly 0,
    // never poisoned by uninitialized workspace. (rn buffer sized gridDim.x*128.)
    if (hf == 0) rn[R] = valid ? 1.0f / fmaxf(sqrtf(ss), 1e-12f) : 0.0f;
}

// f16 screen GEMM (128x128 tile), 2-phase double-buffered glds staging with counted
// vmcnt + raw barriers (one barrier per ks instead of two syncthreads w/ full drain),
// cross-chunk ks=0 prefetch into buf0 during the epilogue, branchless packed-key top-4
// per (row, 64-col half, split). key = (simbits & KMASK) | iter<<7 | col7.
__global__ __launch_bounds__(256, 3) void gemm_screen_k(
    const unsigned* __restrict__ zh, const unsigned* __restrict__ bh,
    const float* __restrict__ rb,
    int* __restrict__ cand, int N, int nChunks) {

    // 50176 B: buf0 [0,16K) | buf1 [16K,32K) | key SIM 33792 B aliased over [16K,50176)
    __shared__ alignas(16) int smem[12544];
    int* SIMI = smem + 4096;

    const int t = threadIdx.x;
    const int w = t >> 6, lane = t & 63;
    const int wm = w & 1, wn = w >> 1;
    const int quad = lane >> 4, l16 = lane & 15;
    const int split = blockIdx.x, rowblk = blockIdx.y;  // 8 rowblks of a split share one XCD
    const int soff = w * 1024 + lane * 16;

    int t0 = (int)0x80000000, t1 = t0, t2 = t0, t3 = t0;

    // prologue: stage ks=0 of first chunk into buf0
    {
        const char* gA = (const char*)zh + (size_t)(rowblk * 16) * 8192;
        const char* gB = (const char*)bh + (size_t)(split * 16) * 8192;
        glds16(gA + soff,        (char*)smem + soff);
        glds16(gA + 4096 + soff, (char*)smem + 4096 + soff);
        glds16(gB + soff,        (char*)smem + 8192 + soff);
        glds16(gB + 4096 + soff, (char*)smem + 12288 + soff);
    }

    int iter = 0;
    for (int chunk = split; chunk < nChunks; chunk += NS, ++iter) {
        f32x4 acc[4][4];
        #pragma unroll
        for (int mi = 0; mi < 4; ++mi)
            #pragma unroll
            for (int ni = 0; ni < 4; ++ni) acc[mi][ni] = (f32x4){0.f, 0.f, 0.f, 0.f};
        float rbv[4];

        #pragma unroll 2
        for (int ks = 0; ks < 16; ++ks) {
            // buf[ks&1] fully staged once all waves pass this barrier (each drained its own
            // glds via vmcnt(0); those loads were issued a full iteration ago -> ~no stall).
            KBAR();
            if (ks < 15) {
                // stage next ks into the other buffer; all waves finished READING it at
                // ks-1 before they could reach the barrier above.
                const char* gA = (const char*)zh + (size_t)(rowblk * 16 + ks + 1) * 8192;
                const char* gB = (const char*)bh + (size_t)(chunk * 16 + ks + 1) * 8192;
                char* l = (char*)smem + (((ks & 1) ^ 1) << 14);
                glds16(gA + soff,        l + soff);
                glds16(gA + 4096 + soff, l + 4096 + soff);
                glds16(gB + soff,        l + 8192 + soff);
                glds16(gB + 4096 + soff, l + 12288 + soff);
            } else if (chunk + NS < nChunks) {
                // cross-chunk prefetch: ks=0 of next chunk into buf0 (disjoint from SIM,
                // lands during the epilogue; consumed at next chunk's ks=0 KBAR).
                const char* gA = (const char*)zh + (size_t)(rowblk * 16) * 8192;
                const char* gB = (const char*)bh + (size_t)((chunk + NS) * 16) * 8192;
                glds16(gA + soff,        (char*)smem + soff);
                glds16(gA + 4096 + soff, (char*)smem + 4096 + soff);
                glds16(gB + soff,        (char*)smem + 8192 + soff);
                glds16(gB + 4096 + soff, (char*)smem + 12288 + soff);
            }
            if (ks == 0) {
                // hoisted column-norm loads: consumed ~15 iterations later in the epilogue,
                // keeps the epilogue free of vmem waits. OOB-safe: rb sized nChunks*128.
                #pragma unroll
                for (int ni = 0; ni < 4; ++ni)
                    rbv[ni] = rb[chunk * 128 + wn * 64 + ni * 16 + l16];
            }

            const unsigned short* A  = (const unsigned short*)((const char*)smem + ((ks & 1) << 14));
            const unsigned short* Bb = (const unsigned short*)((const char*)smem + ((ks & 1) << 14) + 8192);
            f16x8 af[4], bf[4];
            #pragma unroll
            for (int mi = 0; mi < 4; ++mi)
                af[mi] = __builtin_bit_cast(f16x8,
                    *(const i32x4*)(A + (wm * 64 + mi * 16 + l16) * 32 + quad * 8));
            #pragma unroll
            for (int ni = 0; ni < 4; ++ni)
                bf[ni] = __builtin_bit_cast(f16x8,
                    *(const i32x4*)(Bb + (wn * 64 + ni * 16 + l16) * 32 + quad * 8));
            #pragma unroll
            for (int mi = 0; mi < 4; ++mi)
                #pragma unroll
                for (int ni = 0; ni < 4; ++ni)
                    acc[mi][ni] = __builtin_amdgcn_mfma_f32_16x16x32_f16(af[mi], bf[ni], acc[mi][ni], 0, 0, 0);
        }

        // epilogue: 2 passes x 64 cols, column-major key-SIM, top-4 via 1 max + 3 med3.
        // EBAR keeps the cross-chunk glds prefetch in flight (lgkm-only publish).
        const int iterTag = iter << 7;
        #pragma unroll
        for (int p = 0; p < 2; ++p) {
            EBAR();   // waves done reading buf1 frags / prior-pass SIM before overwrite
            #pragma unroll
            for (int nj = 0; nj < 2; ++nj) {
                const int ni = p * 2 + nj;
                const int cCol = wn * 64 + ni * 16 + l16;       // col-in-chunk, 7 bits
                const int tagc = iterTag | cCol;                 // tag folded at keygen
                const float rv = rbv[ni];
                const int cp = wn * 32 + nj * 16 + l16;          // col slot in this pass
                #pragma unroll
                for (int mi = 0; mi < 4; ++mi) {
                    i32x4 kv;
                    #pragma unroll
                    for (int rr = 0; rr < 4; ++rr) {
                        float v = acc[mi][ni][rr] * rv;
                        kv[rr] = (__float_as_int(v) & KMASK) | tagc;
                    }
                    *(i32x4*)(SIMI + cp * SPITCH + wm * 64 + mi * 16 + quad * 4) = kv;
                }
            }
            EBAR();   // SIM writes published
            {
                const int r = t >> 1, h = t & 1;
                const int* s = SIMI + (h * 32) * SPITCH + r;
                #pragma unroll
                for (int j = 0; j < 32; ++j) {
                    int kk = s[j * SPITCH];
                    // sorted-insert into t0>=t1>=t2>=t3: all four ops independent (ILP 4)
                    int n1 = med3(kk, t0, t1);
                    int n2 = med3(kk, t1, t2);
                    int n3 = med3(kk, t2, t3);
                    t0 = imax(kk, t0);
                    t1 = n1; t2 = n2; t3 = n3;
                }
            }
        }
    }

    const int r = t >> 1, h = t & 1;
    i32x4 outk = { t0, t1, t2, t3 };
    *(i32x4*)(cand + (((size_t)(rowblk * 128 + r) * NS + split) * 2 + h) * 4) = outk;
}

// per row: pop exact top-32 of 768 packed keys, exact fp32 rescore, final top-5
__global__ __launch_bounds__(256) void merge_rescore_k(
    const int* __restrict__ cand,
    const float* __restrict__ z, const float* __restrict__ bank,
    const float* __restrict__ rz, const float* __restrict__ rb,
    const int* __restrict__ labels, float* __restrict__ out, int BK, int N) {

    __shared__ float zrow[DDIM];
    __shared__ int   idxs[32];
    __shared__ float dots[32];

    const int row = blockIdx.x;
    const int t = threadIdx.x, w = t >> 6, lane = t & 63;

    {   float2 v = *(const float2*)(z + (size_t)row * DDIM + t * 2);
        zrow[t * 2] = v.x; zrow[t * 2 + 1] = v.y; }

    if (w == 0) {
        int k[12];
        const int* cp = cand + (size_t)row * (NS * 2 * 4) + lane * 12;
        #pragma unroll
        for (int q = 0; q < 12; ++q) k[q] = cp[q];
        for (int r = 0; r < 32; ++r) {
            int lk = k[0], lq = 0;
            #pragma unroll
            for (int q = 1; q < 12; ++q) if (k[q] > lk) { lk = k[q]; lq = q; }
            int wk = lk, wl = lane, wq = lq;
            #pragma unroll
            for (int off = 32; off > 0; off >>= 1) {
                int ok = __shfl_xor(wk, off, 64);
                int ol = __shfl_xor(wl, off, 64);
                int oq = __shfl_xor(wq, off, 64);
                if (ok > wk || (ok == wk && ol < wl)) { wk = ok; wl = ol; wq = oq; }
            }
            if (lane == wl) {
                #pragma unroll
                for (int q = 0; q < 12; ++q) if (q == wq) k[q] = (int)0x80000000;
            }
            if (lane == 0) {
                int j = wl * 12 + wq;         // position -> (split, h, slot)
                int split = j >> 3;
                int c = wk & 127, it = (wk >> 7) & 15;
                int gi = (it * NS + split) * 128 + c;
                idxs[r] = gi < N ? gi : 0;    // statistically impossible, fault-guard only
            }
        }
    }
    __syncthreads();

    // exact fp32 raw dot for the 32 survivors: wave w handles w*8..w*8+7
    #pragma unroll
    for (int jj = 0; jj < 8; ++jj) {
        const int ci = idxs[w * 8 + jj];
        const float* br = bank + (size_t)ci * DDIM + lane * 8;
        float4 x0 = *(const float4*)br;
        float4 x1 = *(const float4*)(br + 4);
        const float* zz = zrow + lane * 8;
        float4 z0 = *(const float4*)zz;
        float4 z1 = *(const float4*)(zz + 4);
        float s = x0.x*z0.x + x0.y*z0.y + x0.z*z0.z + x0.w*z0.w
                + x1.x*z1.x + x1.y*z1.y + x1.z*z1.z + x1.w*z1.w;
        #pragma unroll
        for (int off = 32; off > 0; off >>= 1) s += __shfl_xor(s, off, 64);
        if (lane == 0) dots[w * 8 + jj] = s;
    }
    __syncthreads();

    if (w == 0) {
        const float rzv = rz[row];
        float v; int ii;
        if (lane < 32) { ii = idxs[lane]; v = dots[lane] * rzv * rb[ii]; }
        else           { ii = IMAX;       v = NEG_INF; }
        for (int r = 0; r < 5; ++r) {
            float bv = v; int bi = ii;
            #pragma unroll
            for (int off = 32; off > 0; off >>= 1) {
                float ov = __shfl_xor(bv, off, 64);
                int   oi = __shfl_xor(bi, off, 64);
                if (ov > bv || (ov == bv && oi < bi)) { bv = ov; bi = oi; }
            }
            if (v == bv && ii == bi) { v = NEG_INF; ii = IMAX; }
            if (lane == 0) {
                out[(size_t)row * 5 + r]          = (float)bi;
                out[BK + (size_t)row * 5 + r]     = bv;
                out[2 * BK + (size_t)row * 5 + r] = (float)labels[bi];
            }
        }
    }
}

extern "C" void kernel_launch(void* const* d_in, const int* in_sizes, int n_in,
                              void* d_out, int out_size, void* d_ws, size_t ws_size,
                              hipStream_t stream) {
    const float* z    = (const float*)d_in[0];
    const float* bank = (const float*)d_in[1];
    const int*   lab  = (const int*)d_in[2];
    const int B = in_sizes[0] / DDIM;     // 1024
    const int N = in_sizes[1] / DDIM;     // 100000
    const int BK = out_size / 3;          // 5120
    const int nChunks = (N + 127) >> 7;   // 782
    float* out = (float*)d_out;
    char* ws = (char*)d_ws;

    const size_t o_rz = 0;                                       // B floats (pad 4K)
    const size_t o_rb = 4096;                                    // nChunks*128 floats
    const size_t o_zh = o_rb + (size_t)nChunks * 128 * 4;        // z f16 tile (1 MB)
    const size_t o_bh = o_zh + (size_t)(B / 128) * 16 * 8192;    // bank f16 tile (102.5 MB)
    const size_t o_cv = o_bh + (size_t)nChunks * 16 * 8192;      // cand keys (3 MB)

    float* rz = (float*)(ws + o_rz);
    float* rb = (float*)(ws + o_rb);
    unsigned* zh = (unsigned*)(ws + o_zh);
    unsigned* bh = (unsigned*)(ws + o_bh);
    int* cand = (int*)(ws + o_cv);

    split_tile_k<<<nChunks, 256, 0, stream>>>(bank, bh, rb, N);
    split_tile_k<<<B / 128, 256, 0, stream>>>(z, zh, rz, B);
    gemm_screen_k<<<dim3(NS, B / 128), 256, 0, stream>>>(zh, bh, rb, cand, N, nChunks);
    merge_rescore_k<<<B, 256, 0, stream>>>(cand, z, bank, rz, rb, lab, out, BK, N);
}